// Round 5
// baseline (864.009 us; speedup 1.0000x reference)
//
#include <hip/hip_runtime.h>
#include <cstdint>

#define N 8192
#define NT 128      // 64-col chunks per row (N/64)
typedef unsigned long long u64;
typedef unsigned int u32;
typedef u32 u32x4 __attribute__((ext_vector_type(4)));

// ---------------------------------------------------------------------------
// K1: rank by counting, keys recomputed inline from scores (descending score,
// stable ascending index). Partial counts per y-slab -> rankpart[8][N].
// ---------------------------------------------------------------------------
__global__ __launch_bounds__(256) void k_rank(const float* __restrict__ scores,
                                              int* __restrict__ rankpart) {
  __shared__ u64 tile[1024];
  int e = blockIdx.x * 256 + threadIdx.x;
  int j0 = blockIdx.y * 1024;
  for (int t = threadIdx.x; t < 1024; t += 256) {
    int j = j0 + t;
    tile[t] = ((u64)__float_as_uint(scores[j]) << 32) | (unsigned)(0xFFFFFFFFu - (unsigned)j);
  }
  __syncthreads();
  u64 ke = ((u64)__float_as_uint(scores[e]) << 32) | (unsigned)(0xFFFFFFFFu - (unsigned)e);
  int c = 0;
#pragma unroll 8
  for (int k = 0; k < 1024; ++k) c += (tile[k] > ke) ? 1 : 0;
  rankpart[blockIdx.y * N + e] = c;
}

// ---------------------------------------------------------------------------
// K2: sum rank partials + scatter into sorted SoA + init aux.
// ---------------------------------------------------------------------------
__global__ __launch_bounds__(256) void k_scatter(const float* __restrict__ boxes,
                                                 const float* __restrict__ scores,
                                                 const int* __restrict__ rankpart,
                                                 float* __restrict__ bx1s, float* __restrict__ by1s,
                                                 float* __restrict__ bx2s, float* __restrict__ by2s,
                                                 float* __restrict__ ss, float* __restrict__ areas,
                                                 int* __restrict__ cnt,
                                                 float* __restrict__ prob,
                                                 u64* __restrict__ pk) {
#pragma clang fp contract(off)
  int i = blockIdx.x * 256 + threadIdx.x;
  if (i >= N) return;
  int r = 0;
#pragma unroll
  for (int q = 0; q < 8; ++q) r += rankpart[q * N + i];
  float x1 = fminf(fmaxf(boxes[i * 4 + 0], 0.0f), 1920.0f);
  float y1 = fminf(fmaxf(boxes[i * 4 + 1], 0.0f), 1080.0f);
  float x2 = fminf(fmaxf(boxes[i * 4 + 2], 0.0f), 1920.0f);
  float y2 = fminf(fmaxf(boxes[i * 4 + 3], 0.0f), 1080.0f);
  bx1s[r] = x1; by1s[r] = y1; bx2s[r] = x2; by2s[r] = y2;
  ss[r] = scores[i];
  areas[r] = (x2 - x1 + 1.0f) * (y2 - y1 + 1.0f);
  cnt[i] = 0;
  prob[i] = 0.0f;
  pk[i] = 0ull;
}

// ---------------------------------------------------------------------------
// K3: adjacency, SYMMETRIC lower-triangle blocks + ballot transpose.
// Band trick (verified absmax 0.0): iou>0.5 <=> 2*inter>uni whenever
// |2*inter-uni| > 1e-6*uni; only in-band lanes take the exact IEEE divide.
// fp contract OFF everywhere; matrix float-exact symmetric.
// ---------------------------------------------------------------------------
__global__ __launch_bounds__(64) void k_adj(const float* __restrict__ bx1s, const float* __restrict__ by1s,
                                            const float* __restrict__ bx2s, const float* __restrict__ by2s,
                                            const float* __restrict__ areas,
                                            u64* __restrict__ mtile,
                                            u64* __restrict__ mrow) {
#pragma clang fp contract(off)
  __shared__ float jx1[64], jy1[64], jx2[64], jy2[64], ja[64];
  int p = blockIdx.x;
  int gy = (int)((sqrtf(8.0f * (float)p + 1.0f) - 1.0f) * 0.5f);
  while ((gy + 1) * (gy + 2) / 2 <= p) ++gy;
  while (gy * (gy + 1) / 2 > p) --gy;
  int gx = p - gy * (gy + 1) / 2;

  int l = threadIdx.x;
  int j = gx * 64 + l;
  jx1[l] = bx1s[j]; jy1[l] = by1s[j]; jx2[l] = bx2s[j]; jy2[l] = by2s[j]; ja[l] = areas[j];
  __syncthreads();
  int i = gy * 64 + l;
  float x1 = bx1s[i], y1 = by1s[i], x2 = bx2s[i], y2 = by2s[i], ai = areas[i];
  u64 bits = 0;
#pragma unroll 4
  for (int jj = 0; jj < 64; ++jj) {
    float ix1 = fmaxf(x1, jx1[jj]);
    float iy1 = fmaxf(y1, jy1[jj]);
    float ix2 = fminf(x2, jx2[jj]);
    float iy2 = fminf(y2, jy2[jj]);
    float iw = fmaxf(ix2 - ix1 + 1.0f, 0.0f);
    float ih = fmaxf(iy2 - iy1 + 1.0f, 0.0f);
    float inter = iw * ih;
    float uni = (ai + ja[jj]) - inter;   // uni > 0 always (areas >= 1)
    float t = inter + inter;             // exact (x2)
    bool gt = t > uni;
    bool amb = fabsf(t - uni) <= 1e-6f * uni;
    if (__ballot(amb) != 0ull) {         // ~never taken
      float iou = inter / uni;           // exact IEEE div, matches numpy
      if (amb) gt = iou > 0.5f;
    }
    bits |= ((u64)gt) << jj;
  }
  mtile[((size_t)gy * NT + gx) * 64 + l] = bits;
  mrow[(size_t)i * NT + gx] = bits;
  if (gx != gy) {
    u64 tb = 0;
#pragma unroll 8
    for (int c = 0; c < 64; ++c) {
      u64 wb = __ballot((bits >> c) & 1ull);
      tb = (l == c) ? wb : tb;
    }
    mtile[((size_t)gx * NT + gy) * 64 + l] = tb;
    mrow[(size_t)(gx * 64 + l) * NT + gy] = tb;
  }
}

// ---------------------------------------------------------------------------
// K4: EXACT single-sweep greedy classification, ONE wave. Same algorithm as
// rounds 2-4 (absmax 0.0 each time); round-4's 580cy/candidate was serial-
// issue VALU/SALU bloat (next_cand's hazard-laden scan + u64 readlane test
// interleaved per element). Restructured to the ~30cy/elem form of the old
// proven k_fix:
//  * BALLOT head test vs distributed head-bitmap D (4 x u32 per lane,
//    matching the row dwordx4 layout). NO below-mask: D only contains heads
//    < j when j is tested, so high bits of D are provably zero.
//  * Head updates inside a UNIFORM scalar branch (ballot result) -- no
//    divergence; skips all update cost for non-heads.
//  * Chunked candidate extraction: per 512-elem group, unsuppressed bits of
//    R (4 x u32 per lane) are compacted ONCE into an LDS list (popc +
//    shfl-prefix + scatter, off the serial path), padded with -1. Sound:
//    R only grows, so filtered elements are genuinely suppressed; in-group
//    suppressions are caught by the exact per-element ballot test.
//  * Rows prefetched by pinned asm global_load_dwordx4 (saddr form),
//    double-buffered 16-element blocks; ONE s_waitcnt vmcnt(16) +
//    sched_barrier(0) per block (16 newer loads stay in flight).
// ---------------------------------------------------------------------------
#define REP16(M) M(0) M(1) M(2) M(3) M(4) M(5) M(6) M(7) M(8) M(9) M(10) M(11) M(12) M(13) M(14) M(15)

__global__ __launch_bounds__(64, 1) void k_sweep(const u64* __restrict__ mrow,
                                                 u64* __restrict__ D) {
  __shared__ int ulist[512 + 64];
  int l = threadIdx.x;
  // lane l owns u32 words 4l..4l+3 (matches row dwordx4: rv.x=word 4l, ...)
  u32 Ra = 0, Rb = 0, Rc = 0, Rd = 0;   // suppressed bitmap
  u32 Da = 0, Db = 0, Dc = 0, Dd = 0;   // head bitmap
  u32 voffl = (u32)(l << 4);            // per-lane byte offset within a row

#define DECLR(q) u32x4 rA##q, rB##q;
  REP16(DECLR)
#undef DECLR
#define DECLJ(q) int jA##q, jB##q;
  REP16(DECLJ)
#undef DECLJ

#define ISSUE1(jv, rq) {                                                      \
    int jc_ = (jv < 0) ? 0 : jv;                                              \
    u32 vo_ = voffl + ((u32)jc_ << 10);                                       \
    asm volatile("global_load_dwordx4 %0, %1, %2"                             \
                 : "=v"(rq) : "v"(vo_), "s"(mrow) : "memory");                \
  }
#define ISSUEA(q) ISSUE1(jA##q, rA##q)
#define ISSUEB(q) ISSUE1(jB##q, rB##q)
#define RLA(q) jA##q = __builtin_amdgcn_readlane(vnext, q);
#define RLB(q) jB##q = __builtin_amdgcn_readlane(vnext, q);

// head test: row & D. Exact: D holds exactly the heads < j at j's turn
// (ascending processing), so no masking needed. Update branch is uniform.
#define PROC1(jv, rv) {                                                       \
    int j_ = jv;                                                              \
    u32 h_ = (rv.x & Da) | (rv.y & Db) | (rv.z & Dc) | (rv.w & Dd);           \
    u64 bal_ = __ballot(h_ != 0u);                                            \
    if (j_ >= 0 && bal_ == 0ull) {      /* uniform: j is a head */            \
      int slot_ = (j_ >> 5) & 3;                                              \
      u32 vbit_ = (l == ((j_ >> 7) & 63)) ? (1u << (j_ & 31)) : 0u;           \
      if (slot_ == 0) Da |= vbit_;                                            \
      else if (slot_ == 1) Db |= vbit_;                                       \
      else if (slot_ == 2) Dc |= vbit_;                                       \
      else Dd |= vbit_;                                                       \
      Ra |= rv.x; Rb |= rv.y; Rc |= rv.z; Rd |= rv.w;                         \
    } }
#define PROCA(q) PROC1(jA##q, rA##q)
#define PROCB(q) PROC1(jB##q, rB##q)

#define WAIT16 { asm volatile("s_waitcnt vmcnt(16)" ::: "memory");            \
                 __builtin_amdgcn_sched_barrier(0); }

  for (int g = 0; g < 16; ++g) {
    // ---- extraction: candidates = unsuppressed bits of group g's 16 words
    bool in_ = ((l >> 2) == g);
    u32 c0 = in_ ? ~Ra : 0u;
    u32 c1 = in_ ? ~Rb : 0u;
    u32 c2 = in_ ? ~Rc : 0u;
    u32 c3 = in_ ? ~Rd : 0u;
    int cnt = __popc(c0) + __popc(c1) + __popc(c2) + __popc(c3);
    int pre = cnt;
#pragma unroll
    for (int d = 1; d < 64; d <<= 1) {
      int v = __shfl_up(pre, d);
      if (l >= d) pre += v;
    }
    int Mg = __shfl(pre, 63);
    int off = pre - cnt;
    ulist[Mg + l] = -1;                 // 64 pads (disjoint from [0,Mg))
    int jb = l * 128;                   // j of word 4l, bit 0
    while (c0) { int b = __builtin_ctz(c0); c0 &= c0 - 1; ulist[off++] = jb + b; }
    while (c1) { int b = __builtin_ctz(c1); c1 &= c1 - 1; ulist[off++] = jb + 32 + b; }
    while (c2) { int b = __builtin_ctz(c2); c2 &= c2 - 1; ulist[off++] = jb + 64 + b; }
    while (c3) { int b = __builtin_ctz(c3); c3 &= c3 - 1; ulist[off++] = jb + 96 + b; }
    if (Mg == 0) continue;

    // ---- prime two 16-element blocks
    int vnext = ulist[l & 15];
    REP16(RLA) REP16(ISSUEA)
    vnext = ulist[16 + (l & 15)];
    REP16(RLB) REP16(ISSUEB)

    int m = 0;
    while (true) {
      WAIT16                                  // block A's rows resident
      vnext = ulist[m + 32 + (l & 15)];       // next-next block's indices
      __builtin_amdgcn_sched_barrier(0);
      REP16(PROCA)
      REP16(RLA) REP16(ISSUEA)
      m += 16;
      if (m >= Mg) break;
      WAIT16
      vnext = ulist[m + 32 + (l & 15)];
      __builtin_amdgcn_sched_barrier(0);
      REP16(PROCB)
      REP16(RLB) REP16(ISSUEB)
      m += 16;
      if (m >= Mg) break;
    }
  }

  asm volatile("s_waitcnt vmcnt(0)" ::: "memory");   // drain before endpgm
  __builtin_amdgcn_sched_barrier(0);
  D[2 * l] = ((u64)Db << 32) | (u64)Da;     // u64 word 2l   = u32 words 4l,4l+1
  D[2 * l + 1] = ((u64)Dd << 32) | (u64)Dc; // u64 word 2l+1 = u32 words 4l+2,4l+3
}

// ---------------------------------------------------------------------------
// K5: parallel cluster assignment + segment atomics. cluster[j] = first head
// adjacent to j (head index provably <= j) -> scan only tiles k <= gy.
// Fused "first index at cluster-max y2" via ONE packed u64 atomicMax:
// (y2_bits << 32) | ~j  -- y2 >= 0 so uint order == float order; tie -> min j.
// ---------------------------------------------------------------------------
__global__ __launch_bounds__(256) void k_cluster(const u64* __restrict__ mtile,
                                                 const u64* __restrict__ D,
                                                 const float* __restrict__ ss,
                                                 const float* __restrict__ by2s,
                                                 int* __restrict__ cluster,
                                                 int* __restrict__ cnt,
                                                 float* __restrict__ prob,
                                                 u64* __restrict__ pk) {
  __shared__ u64 hlds[NT];
  __shared__ int red[4][64];
  int gy = blockIdx.x;
  if (threadIdx.x < NT) hlds[threadIdx.x] = D[threadIdx.x];
  __syncthreads();
  int w = threadIdx.x >> 6, r = threadIdx.x & 63;
  int best = 0x7fffffff;
  for (int k = w; k <= gy; k += 4) {      // per-group candidates ascend with k
    u64 v = mtile[((size_t)gy * NT + k) * 64 + r] & hlds[k];
    if (v) { best = k * 64 + __builtin_ctzll(v); break; }
  }
  red[w][r] = best;
  __syncthreads();
  if (w == 0) {
    int b = min(min(red[0][r], red[1][r]), min(red[2][r], red[3][r]));
    int j = gy * 64 + r;
    cluster[j] = b;
    atomicAdd(&cnt[b], 1);
    atomicAdd(&prob[b], ss[j]);
    atomicMax((unsigned long long*)&pk[b],
              ((u64)__float_as_uint(by2s[j]) << 32) | (u64)(0xFFFFFFFFu - (unsigned)j));
  }
}

// ---------------------------------------------------------------------------
// K6: outputs. out[j][0..4] then keep[j] appended (floats 0/1).
// first index recovered from packed atomicMax: ~low32(pk).
// ---------------------------------------------------------------------------
__global__ __launch_bounds__(256) void k_out(const int* __restrict__ cluster,
                                             const float* __restrict__ bx1s, const float* __restrict__ by1s,
                                             const float* __restrict__ bx2s, const float* __restrict__ by2s,
                                             const int* __restrict__ cnt,
                                             const float* __restrict__ prob,
                                             const u64* __restrict__ pk,
                                             const int* __restrict__ num_models,
                                             float* __restrict__ out) {
  int j = blockIdx.x * 256 + threadIdx.x;
  if (j >= N) return;
  int c = cluster[j];
  int nm = num_models[0];
  bool valid = (float)cnt[c] >= (float)nm / 3.0f;
  unsigned fj = 0xFFFFFFFFu - (unsigned)(pk[c] & 0xFFFFFFFFull);
  bool keep = (fj == (unsigned)j) && valid;
  float o0 = 0.f, o1 = 0.f, o2 = 0.f, o3 = 0.f, o4 = 0.f;
  if (keep) {
    o0 = bx1s[j]; o1 = by1s[j]; o2 = bx2s[j]; o3 = by2s[j];
    o4 = prob[c] / (float)nm;
  }
  out[j * 5 + 0] = o0;
  out[j * 5 + 1] = o1;
  out[j * 5 + 2] = o2;
  out[j * 5 + 3] = o3;
  out[j * 5 + 4] = o4;
  out[N * 5 + j] = keep ? 1.0f : 0.0f;
}

// ---------------------------------------------------------------------------
extern "C" void kernel_launch(void* const* d_in, const int* in_sizes, int n_in,
                              void* d_out, int out_size, void* d_ws, size_t ws_size,
                              hipStream_t stream) {
  const float* boxes = (const float*)d_in[0];
  const float* scores = (const float*)d_in[1];
  const int* num_models = (const int*)d_in[2];
  float* out = (float*)d_out;

  char* p = (char*)d_ws;
  auto take = [&](size_t bytes) {
    char* r = p;
    p += (bytes + 255) & ~(size_t)255;
    return r;
  };
  int* rankpart = (int*)take((size_t)8 * N * 4);
  float* bx1s = (float*)take((size_t)N * 4);
  float* by1s = (float*)take((size_t)N * 4);
  float* bx2s = (float*)take((size_t)N * 4);
  float* by2s = (float*)take((size_t)N * 4);
  float* ss   = (float*)take((size_t)N * 4);
  float* areas= (float*)take((size_t)N * 4);
  int* cluster= (int*)take((size_t)N * 4);
  int* cnt    = (int*)take((size_t)N * 4);
  float* prob = (float*)take((size_t)N * 4);
  u64* pk     = (u64*)take((size_t)N * 8);            // packed (y2max, ~first)
  u64* D      = (u64*)take((size_t)NT * 8);           // head bitmap
  u64* mtile  = (u64*)take((size_t)NT * NT * 64 * 8); // 8 MiB tiled adjacency
  u64* mrow   = (u64*)take((size_t)N * NT * 8);       // 8 MiB row-major adjacency

  k_rank<<<dim3(N / 256, 8), 256, 0, stream>>>(scores, rankpart);
  k_scatter<<<N / 256, 256, 0, stream>>>(boxes, scores, rankpart,
                                         bx1s, by1s, bx2s, by2s, ss, areas,
                                         cnt, prob, pk);
  k_adj<<<NT * (NT + 1) / 2, 64, 0, stream>>>(bx1s, by1s, bx2s, by2s, areas, mtile, mrow);
  k_sweep<<<1, 64, 0, stream>>>(mrow, D);
  k_cluster<<<NT, 256, 0, stream>>>(mtile, D, ss, by2s, cluster, cnt, prob, pk);
  k_out<<<N / 256, 256, 0, stream>>>(cluster, bx1s, by1s, bx2s, by2s, cnt, prob, pk, num_models, out);
}

// Round 7
// 862.295 us; speedup vs baseline: 1.0020x; 1.0020x over previous
//
#include <hip/hip_runtime.h>
#include <cstdint>

#define N 8192
#define NT 128      // 64-col chunks per row (N/64)
typedef unsigned long long u64;
typedef unsigned int u32;
typedef u32 u32x4 __attribute__((ext_vector_type(4)));

// ---------------------------------------------------------------------------
// K1: rank by counting, keys recomputed inline from scores (descending score,
// stable ascending index). Partial counts per y-slab -> rankpart[8][N].
// ---------------------------------------------------------------------------
__global__ __launch_bounds__(256) void k_rank(const float* __restrict__ scores,
                                              int* __restrict__ rankpart) {
  __shared__ u64 tile[1024];
  int e = blockIdx.x * 256 + threadIdx.x;
  int j0 = blockIdx.y * 1024;
  for (int t = threadIdx.x; t < 1024; t += 256) {
    int j = j0 + t;
    tile[t] = ((u64)__float_as_uint(scores[j]) << 32) | (unsigned)(0xFFFFFFFFu - (unsigned)j);
  }
  __syncthreads();
  u64 ke = ((u64)__float_as_uint(scores[e]) << 32) | (unsigned)(0xFFFFFFFFu - (unsigned)e);
  int c = 0;
#pragma unroll 8
  for (int k = 0; k < 1024; ++k) c += (tile[k] > ke) ? 1 : 0;
  rankpart[blockIdx.y * N + e] = c;
}

// ---------------------------------------------------------------------------
// K2: sum rank partials + scatter into sorted SoA + init aux.
// ---------------------------------------------------------------------------
__global__ __launch_bounds__(256) void k_scatter(const float* __restrict__ boxes,
                                                 const float* __restrict__ scores,
                                                 const int* __restrict__ rankpart,
                                                 float* __restrict__ bx1s, float* __restrict__ by1s,
                                                 float* __restrict__ bx2s, float* __restrict__ by2s,
                                                 float* __restrict__ ss, float* __restrict__ areas,
                                                 int* __restrict__ cnt,
                                                 float* __restrict__ prob,
                                                 u64* __restrict__ pk) {
#pragma clang fp contract(off)
  int i = blockIdx.x * 256 + threadIdx.x;
  if (i >= N) return;
  int r = 0;
#pragma unroll
  for (int q = 0; q < 8; ++q) r += rankpart[q * N + i];
  float x1 = fminf(fmaxf(boxes[i * 4 + 0], 0.0f), 1920.0f);
  float y1 = fminf(fmaxf(boxes[i * 4 + 1], 0.0f), 1080.0f);
  float x2 = fminf(fmaxf(boxes[i * 4 + 2], 0.0f), 1920.0f);
  float y2 = fminf(fmaxf(boxes[i * 4 + 3], 0.0f), 1080.0f);
  bx1s[r] = x1; by1s[r] = y1; bx2s[r] = x2; by2s[r] = y2;
  ss[r] = scores[i];
  areas[r] = (x2 - x1 + 1.0f) * (y2 - y1 + 1.0f);
  cnt[i] = 0;
  prob[i] = 0.0f;
  pk[i] = 0ull;
}

// ---------------------------------------------------------------------------
// K3: adjacency, SYMMETRIC lower-triangle blocks + ballot transpose.
// Band trick (verified absmax 0.0): iou>0.5 <=> 2*inter>uni whenever
// |2*inter-uni| > 1e-6*uni; only in-band lanes take the exact IEEE divide.
// fp contract OFF everywhere; matrix float-exact symmetric.
// ---------------------------------------------------------------------------
__global__ __launch_bounds__(64) void k_adj(const float* __restrict__ bx1s, const float* __restrict__ by1s,
                                            const float* __restrict__ bx2s, const float* __restrict__ by2s,
                                            const float* __restrict__ areas,
                                            u64* __restrict__ mtile,
                                            u64* __restrict__ mrow) {
#pragma clang fp contract(off)
  __shared__ float jx1[64], jy1[64], jx2[64], jy2[64], ja[64];
  int p = blockIdx.x;
  int gy = (int)((sqrtf(8.0f * (float)p + 1.0f) - 1.0f) * 0.5f);
  while ((gy + 1) * (gy + 2) / 2 <= p) ++gy;
  while (gy * (gy + 1) / 2 > p) --gy;
  int gx = p - gy * (gy + 1) / 2;

  int l = threadIdx.x;
  int j = gx * 64 + l;
  jx1[l] = bx1s[j]; jy1[l] = by1s[j]; jx2[l] = bx2s[j]; jy2[l] = by2s[j]; ja[l] = areas[j];
  __syncthreads();
  int i = gy * 64 + l;
  float x1 = bx1s[i], y1 = by1s[i], x2 = bx2s[i], y2 = by2s[i], ai = areas[i];
  u64 bits = 0;
#pragma unroll 4
  for (int jj = 0; jj < 64; ++jj) {
    float ix1 = fmaxf(x1, jx1[jj]);
    float iy1 = fmaxf(y1, jy1[jj]);
    float ix2 = fminf(x2, jx2[jj]);
    float iy2 = fminf(y2, jy2[jj]);
    float iw = fmaxf(ix2 - ix1 + 1.0f, 0.0f);
    float ih = fmaxf(iy2 - iy1 + 1.0f, 0.0f);
    float inter = iw * ih;
    float uni = (ai + ja[jj]) - inter;   // uni > 0 always (areas >= 1)
    float t = inter + inter;             // exact (x2)
    bool gt = t > uni;
    bool amb = fabsf(t - uni) <= 1e-6f * uni;
    if (__ballot(amb) != 0ull) {         // ~never taken
      float iou = inter / uni;           // exact IEEE div, matches numpy
      if (amb) gt = iou > 0.5f;
    }
    bits |= ((u64)gt) << jj;
  }
  mtile[((size_t)gy * NT + gx) * 64 + l] = bits;
  mrow[(size_t)i * NT + gx] = bits;
  if (gx != gy) {
    u64 tb = 0;
#pragma unroll 8
    for (int c = 0; c < 64; ++c) {
      u64 wb = __ballot((bits >> c) & 1ull);
      tb = (l == c) ? wb : tb;
    }
    mtile[((size_t)gx * NT + gy) * 64 + l] = tb;
    mrow[(size_t)(gx * 64 + l) * NT + gy] = tb;
  }
}

// ---------------------------------------------------------------------------
// K4: EXACT single-sweep greedy classification, ONE wave. Same algorithm +
// structure as round 5 (absmax 0.0). ROOT CAUSE of rounds 3-5's ~650cy/load
// serialization: the "memory" clobber on every load/wait asm made each one an
// opaque mayLoad/mayStore instruction, and SIInsertWaitcnts conservatively
// emitted s_waitcnt vmcnt(0) BEFORE each -- silently rewriting the vmcnt(16)
// pipeline into vmcnt(0)-per-load (VALUBusy 0.024% == 94% memory-wait).
//
// Fix: loads + steady-state waits carry NO "memory" clobber. Volatile asms
// still cannot reorder among themselves (issue order + wait placement stay
// pinned); "=v" outputs carry true deps into PROC; sched_barrier(0) after
// each wait stops register-only PROC hoisting (rule #18). Final drain keeps
// "memory" on purpose (conservative vmcnt(0) there IS the drain, and orders
// the D stores after it).
//
// (Round 6 was an infra failure -- "container failed twice", no adjudication.
// Code re-audited: all addresses in-bounds, all loops counter-bounded, valid
// gfx950 encodings. Resubmitted unchanged for a clean A/B.)
// ---------------------------------------------------------------------------
#define REP16(M) M(0) M(1) M(2) M(3) M(4) M(5) M(6) M(7) M(8) M(9) M(10) M(11) M(12) M(13) M(14) M(15)

__global__ __launch_bounds__(64, 1) void k_sweep(const u64* __restrict__ mrow,
                                                 u64* __restrict__ D) {
  __shared__ int ulist[512 + 64];
  int l = threadIdx.x;
  // lane l owns u32 words 4l..4l+3 (matches row dwordx4: rv.x=word 4l, ...)
  u32 Ra = 0, Rb = 0, Rc = 0, Rd = 0;   // suppressed bitmap
  u32 Da = 0, Db = 0, Dc = 0, Dd = 0;   // head bitmap
  u32 voffl = (u32)(l << 4);            // per-lane byte offset within a row

#define DECLR(q) u32x4 rA##q, rB##q;
  REP16(DECLR)
#undef DECLR
#define DECLJ(q) int jA##q, jB##q;
  REP16(DECLJ)
#undef DECLJ

// NO "memory" clobber: keeps SIInsertWaitcnts from emitting vmcnt(0) drains.
#define ISSUE1(jv, rq) {                                                      \
    int jc_ = (jv < 0) ? 0 : jv;                                              \
    u32 vo_ = voffl + ((u32)jc_ << 10);                                       \
    asm volatile("global_load_dwordx4 %0, %1, %2"                             \
                 : "=v"(rq) : "v"(vo_), "s"(mrow));                           \
  }
#define ISSUEA(q) ISSUE1(jA##q, rA##q)
#define ISSUEB(q) ISSUE1(jB##q, rB##q)
#define RLA(q) jA##q = __builtin_amdgcn_readlane(vnext, q);
#define RLB(q) jB##q = __builtin_amdgcn_readlane(vnext, q);

// head test: row & D. Exact: D holds exactly the heads < j at j's turn
// (ascending processing), so no masking needed. Update branch is uniform.
#define PROC1(jv, rv) {                                                       \
    int j_ = jv;                                                              \
    u32 h_ = (rv.x & Da) | (rv.y & Db) | (rv.z & Dc) | (rv.w & Dd);           \
    u64 bal_ = __ballot(h_ != 0u);                                            \
    if (j_ >= 0 && bal_ == 0ull) {      /* uniform: j is a head */            \
      int slot_ = (j_ >> 5) & 3;                                              \
      u32 vbit_ = (l == ((j_ >> 7) & 63)) ? (1u << (j_ & 31)) : 0u;           \
      if (slot_ == 0) Da |= vbit_;                                            \
      else if (slot_ == 1) Db |= vbit_;                                       \
      else if (slot_ == 2) Dc |= vbit_;                                       \
      else Dd |= vbit_;                                                       \
      Ra |= rv.x; Rb |= rv.y; Rc |= rv.z; Rd |= rv.w;                         \
    } }
#define PROCA(q) PROC1(jA##q, rA##q)
#define PROCB(q) PROC1(jB##q, rB##q)

#define WAIT16 { asm volatile("s_waitcnt vmcnt(16)");                         \
                 __builtin_amdgcn_sched_barrier(0); }

  for (int g = 0; g < 16; ++g) {
    // ---- extraction: candidates = unsuppressed bits of group g's 16 words
    bool in_ = ((l >> 2) == g);
    u32 c0 = in_ ? ~Ra : 0u;
    u32 c1 = in_ ? ~Rb : 0u;
    u32 c2 = in_ ? ~Rc : 0u;
    u32 c3 = in_ ? ~Rd : 0u;
    int cnt = __popc(c0) + __popc(c1) + __popc(c2) + __popc(c3);
    int pre = cnt;
#pragma unroll
    for (int d = 1; d < 64; d <<= 1) {
      int v = __shfl_up(pre, d);
      if (l >= d) pre += v;
    }
    int Mg = __shfl(pre, 63);
    int off = pre - cnt;
    ulist[Mg + l] = -1;                 // 64 pads (disjoint from [0,Mg))
    int jb = l * 128;                   // j of word 4l, bit 0
    while (c0) { int b = __builtin_ctz(c0); c0 &= c0 - 1; ulist[off++] = jb + b; }
    while (c1) { int b = __builtin_ctz(c1); c1 &= c1 - 1; ulist[off++] = jb + 32 + b; }
    while (c2) { int b = __builtin_ctz(c2); c2 &= c2 - 1; ulist[off++] = jb + 64 + b; }
    while (c3) { int b = __builtin_ctz(c3); c3 &= c3 - 1; ulist[off++] = jb + 96 + b; }
    if (Mg == 0) continue;

    // ---- prime two 16-element blocks
    int vnext = ulist[l & 15];
    REP16(RLA) REP16(ISSUEA)
    vnext = ulist[16 + (l & 15)];
    REP16(RLB) REP16(ISSUEB)

    int m = 0;
    while (true) {
      WAIT16                                  // block A's rows resident
      vnext = ulist[m + 32 + (l & 15)];       // next-next block's indices
      __builtin_amdgcn_sched_barrier(0);
      REP16(PROCA)
      REP16(RLA) REP16(ISSUEA)
      m += 16;
      if (m >= Mg) break;
      WAIT16
      vnext = ulist[m + 32 + (l & 15)];
      __builtin_amdgcn_sched_barrier(0);
      REP16(PROCB)
      REP16(RLB) REP16(ISSUEB)
      m += 16;
      if (m >= Mg) break;
    }
  }

  asm volatile("s_waitcnt vmcnt(0)" ::: "memory");   // drain before endpgm
  __builtin_amdgcn_sched_barrier(0);
  D[2 * l] = ((u64)Db << 32) | (u64)Da;     // u64 word 2l   = u32 words 4l,4l+1
  D[2 * l + 1] = ((u64)Dd << 32) | (u64)Dc; // u64 word 2l+1 = u32 words 4l+2,4l+3
}

// ---------------------------------------------------------------------------
// K5: parallel cluster assignment + segment atomics. cluster[j] = first head
// adjacent to j (head index provably <= j) -> scan only tiles k <= gy.
// Fused "first index at cluster-max y2" via ONE packed u64 atomicMax:
// (y2_bits << 32) | ~j  -- y2 >= 0 so uint order == float order; tie -> min j.
// ---------------------------------------------------------------------------
__global__ __launch_bounds__(256) void k_cluster(const u64* __restrict__ mtile,
                                                 const u64* __restrict__ D,
                                                 const float* __restrict__ ss,
                                                 const float* __restrict__ by2s,
                                                 int* __restrict__ cluster,
                                                 int* __restrict__ cnt,
                                                 float* __restrict__ prob,
                                                 u64* __restrict__ pk) {
  __shared__ u64 hlds[NT];
  __shared__ int red[4][64];
  int gy = blockIdx.x;
  if (threadIdx.x < NT) hlds[threadIdx.x] = D[threadIdx.x];
  __syncthreads();
  int w = threadIdx.x >> 6, r = threadIdx.x & 63;
  int best = 0x7fffffff;
  for (int k = w; k <= gy; k += 4) {      // per-group candidates ascend with k
    u64 v = mtile[((size_t)gy * NT + k) * 64 + r] & hlds[k];
    if (v) { best = k * 64 + __builtin_ctzll(v); break; }
  }
  red[w][r] = best;
  __syncthreads();
  if (w == 0) {
    int b = min(min(red[0][r], red[1][r]), min(red[2][r], red[3][r]));
    int j = gy * 64 + r;
    cluster[j] = b;
    atomicAdd(&cnt[b], 1);
    atomicAdd(&prob[b], ss[j]);
    atomicMax((unsigned long long*)&pk[b],
              ((u64)__float_as_uint(by2s[j]) << 32) | (u64)(0xFFFFFFFFu - (unsigned)j));
  }
}

// ---------------------------------------------------------------------------
// K6: outputs. out[j][0..4] then keep[j] appended (floats 0/1).
// first index recovered from packed atomicMax: ~low32(pk).
// ---------------------------------------------------------------------------
__global__ __launch_bounds__(256) void k_out(const int* __restrict__ cluster,
                                             const float* __restrict__ bx1s, const float* __restrict__ by1s,
                                             const float* __restrict__ bx2s, const float* __restrict__ by2s,
                                             const int* __restrict__ cnt,
                                             const float* __restrict__ prob,
                                             const u64* __restrict__ pk,
                                             const int* __restrict__ num_models,
                                             float* __restrict__ out) {
  int j = blockIdx.x * 256 + threadIdx.x;
  if (j >= N) return;
  int c = cluster[j];
  int nm = num_models[0];
  bool valid = (float)cnt[c] >= (float)nm / 3.0f;
  unsigned fj = 0xFFFFFFFFu - (unsigned)(pk[c] & 0xFFFFFFFFull);
  bool keep = (fj == (unsigned)j) && valid;
  float o0 = 0.f, o1 = 0.f, o2 = 0.f, o3 = 0.f, o4 = 0.f;
  if (keep) {
    o0 = bx1s[j]; o1 = by1s[j]; o2 = bx2s[j]; o3 = by2s[j];
    o4 = prob[c] / (float)nm;
  }
  out[j * 5 + 0] = o0;
  out[j * 5 + 1] = o1;
  out[j * 5 + 2] = o2;
  out[j * 5 + 3] = o3;
  out[j * 5 + 4] = o4;
  out[N * 5 + j] = keep ? 1.0f : 0.0f;
}

// ---------------------------------------------------------------------------
extern "C" void kernel_launch(void* const* d_in, const int* in_sizes, int n_in,
                              void* d_out, int out_size, void* d_ws, size_t ws_size,
                              hipStream_t stream) {
  const float* boxes = (const float*)d_in[0];
  const float* scores = (const float*)d_in[1];
  const int* num_models = (const int*)d_in[2];
  float* out = (float*)d_out;

  char* p = (char*)d_ws;
  auto take = [&](size_t bytes) {
    char* r = p;
    p += (bytes + 255) & ~(size_t)255;
    return r;
  };
  int* rankpart = (int*)take((size_t)8 * N * 4);
  float* bx1s = (float*)take((size_t)N * 4);
  float* by1s = (float*)take((size_t)N * 4);
  float* bx2s = (float*)take((size_t)N * 4);
  float* by2s = (float*)take((size_t)N * 4);
  float* ss   = (float*)take((size_t)N * 4);
  float* areas= (float*)take((size_t)N * 4);
  int* cluster= (int*)take((size_t)N * 4);
  int* cnt    = (int*)take((size_t)N * 4);
  float* prob = (float*)take((size_t)N * 4);
  u64* pk     = (u64*)take((size_t)N * 8);            // packed (y2max, ~first)
  u64* D      = (u64*)take((size_t)NT * 8);           // head bitmap
  u64* mtile  = (u64*)take((size_t)NT * NT * 64 * 8); // 8 MiB tiled adjacency
  u64* mrow   = (u64*)take((size_t)N * NT * 8);       // 8 MiB row-major adjacency

  k_rank<<<dim3(N / 256, 8), 256, 0, stream>>>(scores, rankpart);
  k_scatter<<<N / 256, 256, 0, stream>>>(boxes, scores, rankpart,
                                         bx1s, by1s, bx2s, by2s, ss, areas,
                                         cnt, prob, pk);
  k_adj<<<NT * (NT + 1) / 2, 64, 0, stream>>>(bx1s, by1s, bx2s, by2s, areas, mtile, mrow);
  k_sweep<<<1, 64, 0, stream>>>(mrow, D);
  k_cluster<<<NT, 256, 0, stream>>>(mtile, D, ss, by2s, cluster, cnt, prob, pk);
  k_out<<<N / 256, 256, 0, stream>>>(cluster, bx1s, by1s, bx2s, by2s, cnt, prob, pk, num_models, out);
}